// Round 8
// baseline (764.078 us; speedup 1.0000x reference)
//
#include <hip/hip_runtime.h>

#define CH   2048
#define COLS 128          // N*H = 4*32
#define WDIM 48
#define SL   (COLS*CH)    // 262144 elems per state slice
#define NWG  256
#define TPB  512

using f32x4  = __attribute__((ext_vector_type(4))) float;
using bf16x8 = __attribute__((ext_vector_type(8))) short;

__device__ __forceinline__ short f2bf(float f) {
    union { float f; unsigned u; } v; v.f = f;
    unsigned u = v.u;
    u += 0x7fffu + ((u >> 16) & 1u);   // round-to-nearest-even
    return (short)(u >> 16);
}
__device__ __forceinline__ float bf2f(short s) {
    union { unsigned u; float f; } v; v.u = ((unsigned)(unsigned short)s) << 16;
    return v.f;
}

// Wc bf16 from conv_w fp32 (C,C,1,9) taking [:,:,0,4]
__global__ __launch_bounds__(256) void prep_w(const float* __restrict__ cw,
                                              short* __restrict__ wcb) {
    int idx = blockIdx.x * 256 + threadIdx.x;          // o*2048 + c
    wcb[idx] = f2bf(cw[(size_t)idx * 9 + 4]);
}

// state0 = x[:, :, :, 0] in [col][c] layout (bf16 + bf16 correction)
__global__ __launch_bounds__(256) void init0_k(const float* __restrict__ feat,
                                               short* __restrict__ st0,
                                               short* __restrict__ flo0) {
    int i = blockIdx.x * 256 + threadIdx.x;            // col*2048 + c
    int col = i >> 11, c = i & 2047;
    int n = col >> 5, h = col & 31;
    float v = feat[((size_t)(n * CH + c) * 32 + h) * WDIM];
    short s = f2bf(v);
    st0[i] = s;
    flo0[i] = f2bf(v - bf2f(s));
}

// Persistent kernel: 8 independent 16-col recurrence groups; each of the 256
// WGs serves TWO groups (a pair) with a shared 32-row A panel, interleaving
// the two chains so chain A's store-drain + flag visibility hides under
// chain B's poll/load/MFMA (flag posted at B's first barrier = drain point).
// Proven R5 handshake: sc1 data stores -> barrier drain -> flag; plain gated loads.
__global__ __launch_bounds__(TPB, 1) void persist_k(
        const short* __restrict__ wcb, const float* __restrict__ feat,
        short* __restrict__ stbuf,     // 95 slices: fwd fl[0..47], bwd at 48+i
        short* __restrict__ flo,       // 48 slices: fl fp32-correction (bf16)
        float* __restrict__ dout,
        const float* __restrict__ bias, const float* __restrict__ pa,
        unsigned* __restrict__ flags)
{
    __shared__ float red[8 * 8 * 65];      // 16.6 KB padded K-split reduce
    __shared__ short sst[16 * 36];         // 1.2 KB  publish transpose

    int wg = blockIdx.x;
    int pr = wg & 3;                       // pair id: chains 2*pr, 2*pr+1
    int mg = wg >> 2;                      // 0..63 M-tile (32 rows)
    int m0 = mg * 32;
    int gA = pr * 2, gB = pr * 2 + 1;
    int t = threadIdx.x;
    int wv = t >> 6, l = t & 63;
    int lc = l & 15, lg = l >> 4;

    // Shared A panel in registers: row = m0+rb*16+lc, k = wv*256+ks*32+8*lg+j
    bf16x8 aR[2][8];
    {
        const short* ab = wcb + (size_t)(m0 + lc) * CH + wv * 256 + 8 * lg;
        #pragma unroll
        for (int rb = 0; rb < 2; ++rb)
            #pragma unroll
            for (int ks = 0; ks < 8; ++ks)
                aR[rb][ks] = *reinterpret_cast<const bf16x8*>(ab + (size_t)rb * 16 * CH + ks * 32);
    }

    // Epilogue mapping: thread owns output (row0, lc); slot = wv
    int slot = wv;
    int row0 = (slot >> 2) * 16 + lg * 4 + (slot & 3);
    int o0 = m0 + row0;
    float b0v = bias[o0];
    float aP = *pa;

    int n0A = gA * 16, n0B = gB * 16;
    int colA = n0A + lc, colB = n0B + lc;
    size_t off0A = (size_t)colA * CH + o0;
    size_t off0B = (size_t)colB * CH + o0;
    size_t boffsA = (size_t)colA * CH + wv * 256 + 8 * lg;
    size_t boffsB = (size_t)colB * CH + wv * 256 + 8 * lg;
    size_t fbA = ((size_t)((colA >> 5) * CH + o0) * 32 + (colA & 31)) * WDIM;
    size_t fbB = ((size_t)((colB >> 5) * CH + o0) * 32 + (colB & 31)) * WDIM;
    size_t soffA = (((size_t)(n0A + (t >> 4)) * CH + m0) >> 1) + (t & 15); // int idx, t<256
    size_t soffB = (((size_t)(n0B + (t >> 4)) * CH + m0) >> 1) + (t & 15);

    int pendG = -1; unsigned pendV = 0;

    // One chain phase: poll 8 producer flags -> plain B load -> MFMA ->
    // barrier (drains previous publish; post pending flag) -> reduce -> epilogue.
    auto corePhase = [&](int g, size_t boffs, const short* src,
                         unsigned pollval, float r0) -> float {
        {
            const unsigned* f = flags + g * 64 + wv * 8 + (l & 7);
            int guard = 0;
            for (;;) {
                unsigned v = __hip_atomic_load(f, __ATOMIC_RELAXED, __HIP_MEMORY_SCOPE_AGENT);
                if (__all((int)(v >= pollval))) break;
                __builtin_amdgcn_s_sleep(1);
                if (++guard > (1 << 20)) break;        // fail visibly, never hang
            }
            __builtin_amdgcn_sched_barrier(0);
        }
        bf16x8 bq[8];
        const short* bp = src + boffs;
        #pragma unroll
        for (int ks = 0; ks < 8; ++ks)
            bq[ks] = *reinterpret_cast<const bf16x8*>(bp + ks * 32);
        f32x4 acc[2] = {};
        #pragma unroll
        for (int ks = 0; ks < 8; ++ks)
            #pragma unroll
            for (int rb = 0; rb < 2; ++rb)
                acc[rb] = __builtin_amdgcn_mfma_f32_16x16x32_bf16(
                              aR[rb][ks], bq[ks], acc[rb], 0, 0, 0);
        __syncthreads();                               // drains prior publish's sc1 stores
        if (pendG >= 0 && t == 0)
            __hip_atomic_store(flags + pendG * 64 + mg, pendV,
                               __ATOMIC_RELAXED, __HIP_MEMORY_SCOPE_AGENT);
        #pragma unroll
        for (int rb = 0; rb < 2; ++rb)
            #pragma unroll
            for (int rg = 0; rg < 4; ++rg)
                red[wv * 520 + (rb * 4 + rg) * 65 + l] = acc[rb][rg];
        __syncthreads();
        float s0 = 0.f;
        #pragma unroll
        for (int w2 = 0; w2 < 8; ++w2) s0 += red[w2 * 520 + slot * 65 + l];
        float v = s0 + b0v; v = (v >= 0.f) ? v : aP * v; v += r0;
        return v;
    };

    auto publish = [&](short* dst, size_t soff_, float v) {
        sst[lc * 36 + row0] = f2bf(v);
        __syncthreads();
        if (t < 256) {
            int sv = reinterpret_cast<const int*>(sst)[(t >> 4) * 18 + (t & 15)];
            __hip_atomic_store(reinterpret_cast<int*>(dst) + soff_, sv,
                               __ATOMIC_RELAXED, __HIP_MEMORY_SCOPE_AGENT);
        }
    };

    float vA = 0.f, vB = 0.f;

    // ---- forward: fl[w] = prelu(Wc@fl[w-1]+b) + x[w] ----
    for (int w = 1; w <= 47; ++w) {
        float rA = feat[fbA + w];
        vA = corePhase(gA, boffsA, stbuf + (size_t)(w - 1) * SL, (unsigned)(w - 1), rA);
        (flo + (size_t)w * SL)[off0A] = f2bf(vA - bf2f(f2bf(vA)));
        publish(stbuf + (size_t)w * SL, soffA, vA);
        pendG = gA; pendV = (unsigned)w;

        float rB = feat[fbB + w];
        vB = corePhase(gB, boffsB, stbuf + (size_t)(w - 1) * SL, (unsigned)(w - 1), rB);
        (flo + (size_t)w * SL)[off0B] = f2bf(vB - bf2f(f2bf(vB)));
        publish(stbuf + (size_t)w * SL, soffB, vB);
        pendG = gB; pendV = (unsigned)w;
    }
    dout[fbA + 47] = vA;                               // out[47] = fl[47]
    dout[fbB + 47] = vB;

    // ---- backward: out[i] = prelu(Wc@state+b) + fl[i] ----
    for (int i = 46; i >= 0; --i) {
        const short* src = (i == 46) ? stbuf + (size_t)47 * SL
                                     : stbuf + (size_t)(48 + i + 1) * SL;
        unsigned pv = (i == 46) ? 47u : (unsigned)(93 - i);
        const short* fbm = stbuf + (size_t)i * SL;
        const short* fom = flo  + (size_t)i * SL;

        float rA = bf2f(fbm[off0A]) + bf2f(fom[off0A]);
        vA = corePhase(gA, boffsA, src, pv, rA);
        dout[fbA + i] = vA;
        if (i > 0) { publish(stbuf + (size_t)(48 + i) * SL, soffA, vA);
                     pendG = gA; pendV = (unsigned)(94 - i); }

        float rB = bf2f(fbm[off0B]) + bf2f(fom[off0B]);
        vB = corePhase(gB, boffsB, src, pv, rB);
        dout[fbB + i] = vB;
        if (i > 0) { publish(stbuf + (size_t)(48 + i) * SL, soffB, vB);
                     pendG = gB; pendV = (unsigned)(94 - i); }
    }
}

extern "C" void kernel_launch(void* const* d_in, const int* in_sizes, int n_in,
                              void* d_out, int out_size, void* d_ws, size_t ws_size,
                              hipStream_t stream) {
    const float* feat = (const float*)d_in[0];
    const float* cw   = (const float*)d_in[1];
    const float* bias = (const float*)d_in[2];
    const float* pa   = (const float*)d_in[3];

    char* ws = (char*)d_ws;
    short* wcb   = (short*)(ws);                 // 8 MB    bf16 Wc
    short* stbuf = (short*)(ws + 8388608);       // 47.5 MB 95 bf16 state slices
    short* flo   = (short*)(ws + 58195968);      // 24 MB   48 bf16 fl-correction slices
    unsigned* flags = (unsigned*)(ws + 83361792);// 2 KB    per-group per-WG step flags
                                                 // total ~79.5 MB (<= 85 MB proven)

    hipMemsetAsync(flags, 0, 4096, stream);
    prep_w<<<16384, 256, 0, stream>>>(cw, wcb);
    init0_k<<<1024, 256, 0, stream>>>(feat, stbuf, flo);

    persist_k<<<NWG, TPB, 0, stream>>>(wcb, feat, stbuf, flo,
                                       (float*)d_out, bias, pa, flags);
}

// Round 9
// 636.139 us; speedup vs baseline: 1.2011x; 1.2011x over previous
//
#include <hip/hip_runtime.h>

#define CH   2048
#define COLS 128          // N*H = 4*32
#define WDIM 48
#define SL   (COLS*CH)    // 262144 elems per w-slice
#define NWG  256
#define TPB  512

using f32x4  = __attribute__((ext_vector_type(4))) float;
using bf16x8 = __attribute__((ext_vector_type(8))) short;

__device__ __forceinline__ short f2bf(float f) {
    union { float f; unsigned u; } v; v.f = f;
    unsigned u = v.u;
    u += 0x7fffu + ((u >> 16) & 1u);   // round-to-nearest-even
    return (short)(u >> 16);
}

// Wc bf16 from conv_w fp32 (C,C,1,9) taking [:,:,0,4]
__global__ __launch_bounds__(256) void prep_w(const float* __restrict__ cw,
                                              short* __restrict__ wcb) {
    int idx = blockIdx.x * 256 + threadIdx.x;          // o*2048 + c
    wcb[idx] = f2bf(cw[(size_t)idx * 9 + 4]);
}

// feature (N,C,H,W) -> x_t[w][col][c], col = n*32 + h
__global__ __launch_bounds__(256) void prep_x(const float* __restrict__ feat,
                                              float* __restrict__ xt) {
    int b = blockIdx.x;
    int col = b >> 5;            // 0..127
    int ct  = b & 31;            // c-tile (64 channels)
    int n = col >> 5, h = col & 31;
    int c0 = ct * 64;
    __shared__ float tile[64][49];
    int t = threadIdx.x;
    const float* base = feat + (((size_t)n * CH + c0) * 32 + h) * WDIM;
    #pragma unroll
    for (int it = 0; it < 3; ++it) {
        int id = it * 256 + t;             // 0..767
        int row = id / 12, w4 = id % 12;
        float4 v = *reinterpret_cast<const float4*>(base + (size_t)row * 1536 + w4 * 4);
        tile[row][w4*4+0] = v.x; tile[row][w4*4+1] = v.y;
        tile[row][w4*4+2] = v.z; tile[row][w4*4+3] = v.w;
    }
    __syncthreads();
    int c = t & 63, wq = t >> 6;
    #pragma unroll
    for (int it = 0; it < 12; ++it) {
        int w = it * 4 + wq;
        xt[((size_t)w * COLS + col) * CH + c0 + c] = tile[c][w];
    }
}

__global__ __launch_bounds__(256) void init0_k(const float* __restrict__ x0,
                                               float* __restrict__ fl0,
                                               short* __restrict__ fb0) {
    int i = blockIdx.x * 256 + threadIdx.x;
    float v = x0[i];
    fl0[i] = v;
    fb0[i] = f2bf(v);
}

// Persistent kernel: 8 independent 16-col chains; each of 256 WGs serves a
// PAIR of chains (gA=2pr, gB=2pr+1) with a shared 32-row A panel. Chain A's
// publish-drain + flag post are deferred into chain B's compute phase (and
// vice versa), hiding the flag round trip that was exposed in R5.
// Handshake (R5-proven): sc1 data stores -> __syncthreads (vmcnt drain) ->
// flag post; consumers poll flags then use plain gated loads (fresh addrs).
__global__ __launch_bounds__(TPB, 1) void persist_k(
        const short* __restrict__ wcb, const float* __restrict__ xt,
        short* __restrict__ flbf, short* __restrict__ bwdb,
        float* __restrict__ fl32, float* __restrict__ outt,
        const float* __restrict__ bias, const float* __restrict__ pa,
        unsigned* __restrict__ flags, int byp)
{
    __shared__ float red[8 * 8 * 65];      // 16.6 KB padded K-split reduce
    __shared__ short sst[16 * 36];         // 1.2 KB  publish transpose

    int wg = blockIdx.x;
    int pr = wg & 3;                       // pair id
    int mg = wg >> 2;                      // 0..63 M-tile (32 rows)
    int m0 = mg * 32;
    int gA = pr * 2, gB = pr * 2 + 1;
    int t = threadIdx.x;
    int wv = t >> 6, l = t & 63;
    int lc = l & 15, lg = l >> 4;

    // Shared A panel: row = m0+rb*16+lc, k = wv*256+ks*32+8*lg+j
    bf16x8 aR[2][8];
    {
        const short* ab = wcb + (size_t)(m0 + lc) * CH + wv * 256 + 8 * lg;
        #pragma unroll
        for (int rb = 0; rb < 2; ++rb)
            #pragma unroll
            for (int ks = 0; ks < 8; ++ks)
                aR[rb][ks] = *reinterpret_cast<const bf16x8*>(ab + (size_t)rb * 16 * CH + ks * 32);
    }

    // Output mapping: thread owns (row0, lc) per chain; slot = wv
    int row0 = (wv >> 2) * 16 + lg * 4 + (wv & 3);
    int o0 = m0 + row0;
    float b0v = bias[o0];
    float aP = *pa;

    int n0A = gA * 16, n0B = gB * 16;
    size_t off0A = (size_t)(n0A + lc) * CH + o0;
    size_t off0B = (size_t)(n0B + lc) * CH + o0;
    size_t boffsA = (size_t)(n0A + lc) * CH + wv * 256 + 8 * lg;
    size_t boffsB = (size_t)(n0B + lc) * CH + wv * 256 + 8 * lg;
    size_t soffA = (((size_t)(n0A + (t >> 4)) * CH + m0) >> 1) + (t & 15);  // int idx
    size_t soffB = (((size_t)(n0B + (t >> 4)) * CH + m0) >> 1) + (t & 15);

    int pendG = -1; unsigned pendV = 0;

    // One chain phase: narrow poll (wave wv polls its 8 k-producers) ->
    // gated B load -> MFMA -> barrier (drain; post pending flag) -> reduce.
    auto corePhase = [&](int g, size_t boffs, const short* src,
                         unsigned pollval, float r0, bool bypass) -> float {
        if (pollval) {
            const unsigned* f = flags + g * 64 + wv * 8 + (l & 7);
            int guard = 0;
            for (;;) {
                unsigned v = __hip_atomic_load(f, __ATOMIC_RELAXED, __HIP_MEMORY_SCOPE_AGENT);
                if (__all((int)(v >= pollval))) break;
                __builtin_amdgcn_s_sleep(1);
                if (++guard > (1 << 20)) break;        // fail visibly, never hang
            }
            __builtin_amdgcn_sched_barrier(0);
        }
        bf16x8 bq[8];
        const short* bp = src + boffs;
        if (!bypass) {
            #pragma unroll
            for (int ks = 0; ks < 8; ++ks)
                bq[ks] = *reinterpret_cast<const bf16x8*>(bp + ks * 32);
        } else {                                        // ping-pong reuse: L2-bypass
            #pragma unroll
            for (int ks = 0; ks < 8; ++ks) {
                union { int i4[4]; bf16x8 v; } u;
                const int* ip = reinterpret_cast<const int*>(bp + ks * 32);
                #pragma unroll
                for (int j = 0; j < 4; ++j)
                    u.i4[j] = __hip_atomic_load(const_cast<int*>(ip) + j,
                                                __ATOMIC_RELAXED, __HIP_MEMORY_SCOPE_AGENT);
                bq[ks] = u.v;
            }
        }
        f32x4 acc[2] = {};
        #pragma unroll
        for (int ks = 0; ks < 8; ++ks)
            #pragma unroll
            for (int rb = 0; rb < 2; ++rb)
                acc[rb] = __builtin_amdgcn_mfma_f32_16x16x32_bf16(
                              aR[rb][ks], bq[ks], acc[rb], 0, 0, 0);
        __syncthreads();                   // drains prior publish's sc1 stores
        if (pendG >= 0 && t == 0)
            __hip_atomic_store(flags + pendG * 64 + mg, pendV,
                               __ATOMIC_RELAXED, __HIP_MEMORY_SCOPE_AGENT);
        #pragma unroll
        for (int rb = 0; rb < 2; ++rb)
            #pragma unroll
            for (int rg = 0; rg < 4; ++rg)
                red[wv * 520 + (rb * 4 + rg) * 65 + l] = acc[rb][rg];
        __syncthreads();
        float s0 = 0.f;
        #pragma unroll
        for (int w2 = 0; w2 < 8; ++w2) s0 += red[w2 * 520 + wv * 65 + l];
        float v = s0 + b0v; v = (v >= 0.f) ? v : aP * v; v += r0;
        return v;
    };

    auto publish = [&](short* dst, size_t soff_, float v) {
        sst[lc * 36 + row0] = f2bf(v);
        __syncthreads();
        if (t < 256) {
            int sv = reinterpret_cast<const int*>(sst)[(t >> 4) * 18 + (t & 15)];
            __hip_atomic_store(reinterpret_cast<int*>(dst) + soff_, sv,
                               __ATOMIC_RELAXED, __HIP_MEMORY_SCOPE_AGENT);
        }
    };

    float vA = 0.f, vB = 0.f;

    // ---- forward: fl[w] = prelu(Wc@fl[w-1]+b) + x[w] ----
    for (int w = 1; w <= 47; ++w) {
        float rA = xt[(size_t)w * SL + off0A];
        vA = corePhase(gA, boffsA, flbf + (size_t)(w - 1) * SL,
                       (unsigned)(w - 1), rA, false);
        fl32[(size_t)w * SL + off0A] = vA;
        publish(flbf + (size_t)w * SL, soffA, vA);
        pendG = gA; pendV = (unsigned)w;

        float rB = xt[(size_t)w * SL + off0B];
        vB = corePhase(gB, boffsB, flbf + (size_t)(w - 1) * SL,
                       (unsigned)(w - 1), rB, false);
        fl32[(size_t)w * SL + off0B] = vB;
        publish(flbf + (size_t)w * SL, soffB, vB);
        pendG = gB; pendV = (unsigned)w;
    }
    outt[(size_t)47 * SL + off0A] = vA;                // out[47] = fl[47]
    outt[(size_t)47 * SL + off0B] = vB;

    // ---- backward: out[i] = prelu(Wc@state+b) + fl[i] ----
    for (int i = 46; i >= 0; --i) {
        const short* src = (i == 46) ? flbf + (size_t)47 * SL
                                     : bwdb + (size_t)(byp ? ((i + 1) & 1) : (i + 1)) * SL;
        unsigned pv = (i == 46) ? 47u : (unsigned)(93 - i);
        bool byl = byp && (i < 45);                    // reused addr from i+2's write
        short* nxt = bwdb + (size_t)(byp ? (i & 1) : i) * SL;

        float rA = fl32[(size_t)i * SL + off0A];
        vA = corePhase(gA, boffsA, src, pv, rA, byl);
        outt[(size_t)i * SL + off0A] = vA;
        if (i > 0) { publish(nxt, soffA, vA);
                     pendG = gA; pendV = (unsigned)(94 - i); }

        float rB = fl32[(size_t)i * SL + off0B];
        vB = corePhase(gB, boffsB, src, pv, rB, byl);
        outt[(size_t)i * SL + off0B] = vB;
        if (i > 0) { publish(nxt, soffB, vB);
                     pendG = gB; pendV = (unsigned)(94 - i); }
    }
}

// out_t[w][col][c] -> dout (N,C,H,W)
__global__ __launch_bounds__(256) void fin_t(const float* __restrict__ ot,
                                             float* __restrict__ dout) {
    int b = blockIdx.x;
    int col = b >> 5, ct = b & 31;
    int n = col >> 5, h = col & 31;
    int c0 = ct * 64;
    __shared__ float tile[48][65];
    int t = threadIdx.x;
    int c = t & 63, wq = t >> 6;
    #pragma unroll
    for (int it = 0; it < 12; ++it) {
        int w = it * 4 + wq;
        tile[w][c] = ot[((size_t)w * COLS + col) * CH + c0 + c];
    }
    __syncthreads();
    float* base = dout + (((size_t)n * CH + c0) * 32 + h) * WDIM;
    #pragma unroll
    for (int it = 0; it < 3; ++it) {
        int id = it * 256 + t;
        int row = id / 12, w4 = id % 12;
        float4 v;
        v.x = tile[w4*4+0][row]; v.y = tile[w4*4+1][row];
        v.z = tile[w4*4+2][row]; v.w = tile[w4*4+3][row];
        *reinterpret_cast<float4*>(base + (size_t)row * 1536 + w4 * 4) = v;
    }
}

extern "C" void kernel_launch(void* const* d_in, const int* in_sizes, int n_in,
                              void* d_out, int out_size, void* d_ws, size_t ws_size,
                              hipStream_t stream) {
    const float* feat = (const float*)d_in[0];
    const float* cw   = (const float*)d_in[1];
    const float* bias = (const float*)d_in[2];
    const float* pa   = (const float*)d_in[3];

    float* fl32 = (float*)d_out;                 // 48 fp32 fl slices live in d_out

    char* ws = (char*)d_ws;
    short* wcb  = (short*)(ws);                  // 8 MB    bf16 Wc
    float* xt   = (float*)(ws + 8388608);        // 48 MB   x_t (reused as out_t)
    short* flbf = (short*)(ws + 58720256);       // 24 MB   bf16 forward states (48)
    unsigned* flags = (unsigned*)(ws + 83886080);// 4 KB    per-chain per-WG step flags
    short* bwdb = (short*)(ws + 83890176);       // 23.5 MB backward states (47)
    float* outt = xt;

    const size_t needed_full = 83890176ull + 47ull * SL * 2;
    int byp = (ws_size < needed_full) ? 1 : 0;

    hipMemsetAsync(flags, 0, 4096, stream);
    prep_w<<<16384, 256, 0, stream>>>(cw, wcb);
    prep_x<<<4096, 256, 0, stream>>>(feat, xt);
    init0_k<<<1024, 256, 0, stream>>>(xt, fl32, flbf);   // fl[0] = x[0]

    persist_k<<<NWG, TPB, 0, stream>>>(wcb, xt, flbf, bwdb, fl32, outt,
                                       bias, pa, flags, byp);

    fin_t<<<4096, 256, 0, stream>>>(outt, (float*)d_out);
}